// Round 2
// 102.270 us; speedup vs baseline: 1.0243x; 1.0243x over previous
//
#include <hip/hip_runtime.h>

// NegativeSelection: score[i] = max(min_j ||x_i - s_j|| - 0.1, 0)
// N=16384, M=8192, D=128, fp32 in/out.
//
// Strategy: d2 = a2 + b2 - 2*dot. dot via fp16 MFMA (32x32x16), A pre-negated
// so acc = C_init(b2/2) + (-x)·s = b2/2 - dot; min over j tracked per row.
// final: d2 = a2 + 2*min, score = max(sqrt(max(d2,0)) - 0.1, 0).
//
// This revision: single-barrier double-buffered B staging (tile t+1 loads
// issued BEFORE tile t's compute so the barrier's vmcnt(0) drain is free),
// ki=0 peeled so b2-broadcast feeds MFMA C directly, b2 prefetched across
// the barrier, a2 computed in prep so final_kernel doesn't re-read x.
//
// ws layout: Aws fp16 [N*128] (4 MB, tiled [k8][row][8], NEGATED)
//            Bws fp16 [M*128] (2 MB, same tiling)
//            b2h  f32 [M]     (0.5*rownorm² of self)
//            Pmin f32 [N*8]   (partial mins: 4 slices × 2 col-waves)
//            a2   f32 [N]     (rownorm² of x)
// total ~7.0 MB.

using half_t = _Float16;
typedef _Float16 half8 __attribute__((ext_vector_type(8)));
typedef float floatx16 __attribute__((ext_vector_type(16)));

#define TILE_ELEMS (128 * 128)

__device__ __forceinline__ void async_load16(const void* g, void* l) {
    __builtin_amdgcn_global_load_lds(
        (const __attribute__((address_space(1))) void*)g,
        (__attribute__((address_space(3))) void*)l, 16, 0, 0);
}

// One block per 128x128 tile. Converts fp32 -> fp16 into tiled layout
// [k8][row][8] (chunk c = k8*128+row stored at element c*8). A is negated.
// B tiles: b2h = 0.5 * sum(row^2). A tiles: a2 = sum(row^2).
__global__ __launch_bounds__(256) void prep_kernel(
    const float* __restrict__ x, const float* __restrict__ self,
    half_t* __restrict__ Aws, half_t* __restrict__ Bws,
    float* __restrict__ b2h, float* __restrict__ a2, int Atiles)
{
    __shared__ float part[256];
    int tile = blockIdx.x;
    int tid  = threadIdx.x;
    bool isB = tile >= Atiles;
    int bt   = tile - Atiles;
    const float* src = isB ? (self + (size_t)bt * TILE_ELEMS)
                           : (x    + (size_t)tile * TILE_ELEMS);
    half_t* dst = isB ? (Bws + (size_t)bt * TILE_ELEMS)
                      : (Aws + (size_t)tile * TILE_ELEMS);
    float sgn = isB ? 1.f : -1.f;

    int rowt = tid & 127;       // this thread's row (constant across i)
    int k8b  = tid >> 7;        // 0 or 1
    float ss = 0.f;
    #pragma unroll
    for (int i = 0; i < 8; ++i) {
        int k8 = i * 2 + k8b;
        const float4* p = (const float4*)(src + rowt * 128 + k8 * 8);
        float4 f0 = p[0];
        float4 f1 = p[1];
        half8 h;
        h[0] = (half_t)(sgn * f0.x); h[1] = (half_t)(sgn * f0.y);
        h[2] = (half_t)(sgn * f0.z); h[3] = (half_t)(sgn * f0.w);
        h[4] = (half_t)(sgn * f1.x); h[5] = (half_t)(sgn * f1.y);
        h[6] = (half_t)(sgn * f1.z); h[7] = (half_t)(sgn * f1.w);
        *(half8*)(dst + (size_t)(i * 256 + tid) * 8) = h;  // identity: coalesced
        ss += f0.x*f0.x + f0.y*f0.y + f0.z*f0.z + f0.w*f0.w;
        ss += f1.x*f1.x + f1.y*f1.y + f1.z*f1.z + f1.w*f1.w;
    }
    part[tid] = ss;
    __syncthreads();
    if (tid < 128) {
        float tot = part[tid] + part[tid + 128];
        if (isB) b2h[bt * 128 + tid] = 0.5f * tot;
        else     a2[tile * 128 + tid] = tot;
    }
}

// Grid: (N/128 row-blocks, 4 M-slices). Block 256 = 4 waves in 2x2.
// Wave (wr,wc) computes rows wr*64..+64 x cols wc*64..+64 per B tile.
// A fragments in registers for the whole block; B double-buffered in LDS
// via global_load_lds with a single barrier per iteration (loads for tile
// t+1 issued before tile t's MFMAs, so the barrier drain costs ~nothing).
__global__ __launch_bounds__(256, 2) void min_gemm_kernel(
    const half_t* __restrict__ Aws, const half_t* __restrict__ Bws,
    const float* __restrict__ b2h, float* __restrict__ Pmin,
    int Mslice)
{
    __shared__ half_t Bsh[2][TILE_ELEMS];  // 2 x 32 KB, layout [k8][row][8]

    int tid  = threadIdx.x;
    int lane = tid & 63;
    int wid  = tid >> 6;
    int wr   = wid >> 1, wc = wid & 1;
    int ln31 = lane & 31, lh = lane >> 5;

    // A fragments: rows wr*64 + rt*32 + ln31, k = k8*8.., held in regs.
    const half_t* Atile = Aws + (size_t)blockIdx.x * TILE_ELEMS;
    half8 areg[2][8];
    #pragma unroll
    for (int rt = 0; rt < 2; ++rt)
        #pragma unroll
        for (int ki = 0; ki < 8; ++ki) {
            int k8  = ki * 2 + lh;
            int row = wr * 64 + rt * 32 + ln31;
            areg[rt][ki] = *(const half8*)(Atile + (size_t)(k8 * 128 + row) * 8);
        }

    float minacc[2][16];
    #pragma unroll
    for (int rt = 0; rt < 2; ++rt)
        #pragma unroll
        for (int r = 0; r < 16; ++r) minacc[rt][r] = 1e30f;

    int iters = Mslice >> 7;
    int s = blockIdx.y;
    const half_t* Bbase = Bws + (size_t)s * iters * TILE_ELEMS;

    // Prologue: stage tile 0 into Bsh[0].
    #pragma unroll
    for (int j = 0; j < 8; ++j) {
        int seg = wid * 8 + j;                 // 0..31, each 1 KB
        async_load16(Bbase + (size_t)(seg * 64 + lane) * 8,
                     &Bsh[0][(size_t)seg * 512]);
    }
    __syncthreads();   // vmcnt(0) drain: tile 0 landed

    // b2 pair for it=0 (prefetched each iteration thereafter).
    float b2v0 = b2h[s * Mslice + wc * 64 + ln31];
    float b2v1 = b2h[s * Mslice + wc * 64 + 32 + ln31];

    int cur = 0;
    for (int it = 0; it < iters; ++it) {
        // Issue next tile's loads FIRST — they complete under this tile's
        // MFMAs, so the end-of-iter barrier's vmcnt(0) drain is cheap.
        if (it + 1 < iters) {
            const half_t* Bt = Bbase + (size_t)(it + 1) * TILE_ELEMS;
            #pragma unroll
            for (int j = 0; j < 8; ++j) {
                int seg = wid * 8 + j;
                async_load16(Bt + (size_t)(seg * 64 + lane) * 8,
                             &Bsh[cur ^ 1][(size_t)seg * 512]);
            }
        }
        // Prefetch next iteration's b2 pair (loads can't be hoisted
        // across the barrier by the compiler).
        int nit = (it + 1 < iters) ? it + 1 : it;
        float nb0 = b2h[s * Mslice + nit * 128 + wc * 64 + ln31];
        float nb1 = b2h[s * Mslice + nit * 128 + wc * 64 + 32 + ln31];

        // Broadcast b2/2 into C vectors; ki=0 is peeled so these feed the
        // MFMA C operand directly (no per-acc copy).
        floatx16 c0, c1;
        #pragma unroll
        for (int r = 0; r < 16; ++r) { c0[r] = b2v0; c1[r] = b2v1; }

        const half_t* Bs = &Bsh[cur][0];

        floatx16 acc00, acc01, acc10, acc11;
        {
            int k8 = lh;  // ki = 0
            half8 bf0 = *(const half8*)(Bs + (size_t)(k8 * 128 + wc * 64 + ln31) * 8);
            half8 bf1 = *(const half8*)(Bs + (size_t)(k8 * 128 + wc * 64 + 32 + ln31) * 8);
            acc00 = __builtin_amdgcn_mfma_f32_32x32x16_f16(areg[0][0], bf0, c0, 0, 0, 0);
            acc01 = __builtin_amdgcn_mfma_f32_32x32x16_f16(areg[0][0], bf1, c1, 0, 0, 0);
            acc10 = __builtin_amdgcn_mfma_f32_32x32x16_f16(areg[1][0], bf0, c0, 0, 0, 0);
            acc11 = __builtin_amdgcn_mfma_f32_32x32x16_f16(areg[1][0], bf1, c1, 0, 0, 0);
        }
        #pragma unroll
        for (int ki = 1; ki < 8; ++ki) {
            int k8 = ki * 2 + lh;
            half8 bf0 = *(const half8*)(Bs + (size_t)(k8 * 128 + wc * 64 + ln31) * 8);
            half8 bf1 = *(const half8*)(Bs + (size_t)(k8 * 128 + wc * 64 + 32 + ln31) * 8);
            acc00 = __builtin_amdgcn_mfma_f32_32x32x16_f16(areg[0][ki], bf0, acc00, 0, 0, 0);
            acc01 = __builtin_amdgcn_mfma_f32_32x32x16_f16(areg[0][ki], bf1, acc01, 0, 0, 0);
            acc10 = __builtin_amdgcn_mfma_f32_32x32x16_f16(areg[1][ki], bf0, acc10, 0, 0, 0);
            acc11 = __builtin_amdgcn_mfma_f32_32x32x16_f16(areg[1][ki], bf1, acc11, 0, 0, 0);
        }

        // acc = b2/2 - dot; fold into running per-row min (min3-fusible).
        #pragma unroll
        for (int r = 0; r < 16; ++r) {
            minacc[0][r] = fminf(fminf(acc00[r], acc01[r]), minacc[0][r]);
            minacc[1][r] = fminf(fminf(acc10[r], acc11[r]), minacc[1][r]);
        }

        b2v0 = nb0; b2v1 = nb1;

        __syncthreads();   // drains vmcnt(0): tile t+1 landed; Bsh[cur] free
        cur ^= 1;
    }

    // min across the 32 column-lanes; C/D row = (r&3) + 8*(r>>2) + 4*lh.
    #pragma unroll
    for (int rt = 0; rt < 2; ++rt)
        #pragma unroll
        for (int r = 0; r < 16; ++r) {
            float v = minacc[rt][r];
            #pragma unroll
            for (int m = 1; m < 32; m <<= 1)
                v = fminf(v, __shfl_xor(v, m, 64));
            if (ln31 == 0) {
                int row = blockIdx.x * 128 + wr * 64 + rt * 32
                        + (r & 3) + 8 * (r >> 2) + 4 * lh;
                Pmin[(size_t)row * 8 + s * 2 + wc] = v;
            }
        }
}

// One thread per row: min of 8 partials, d2 = a2 + 2*min, sqrt/shift/clamp.
__global__ __launch_bounds__(256) void final_kernel(
    const float* __restrict__ a2, const float* __restrict__ Pmin,
    float* __restrict__ out)
{
    int row = blockIdx.x * 256 + threadIdx.x;
    const float4* pp = (const float4*)(Pmin + (size_t)row * 8);
    float4 p0 = pp[0];
    float4 p1 = pp[1];
    float p = fminf(fminf(fminf(p0.x, p0.y), fminf(p0.z, p0.w)),
                    fminf(fminf(p1.x, p1.y), fminf(p1.z, p1.w)));
    float d2 = a2[row] + 2.f * p;          // a2 + 2*(b2/2 - dot)
    float d  = sqrtf(fmaxf(d2, 0.f));
    out[row] = fmaxf(d - 0.1f, 0.f);
}

extern "C" void kernel_launch(void* const* d_in, const int* in_sizes, int n_in,
                              void* d_out, int out_size, void* d_ws, size_t ws_size,
                              hipStream_t stream)
{
    const float* x    = (const float*)d_in[0];
    const float* self = (const float*)d_in[1];
    float* out        = (float*)d_out;

    int N = in_sizes[0] / 128;   // 16384
    int M = in_sizes[1] / 128;   // 8192
    int Atiles = N / 128;        // 128
    int Btiles = M / 128;        // 64

    char* w      = (char*)d_ws;
    half_t* Aws  = (half_t*)w;
    half_t* Bws  = Aws + (size_t)N * 128;
    float*  b2h  = (float*)(w + (size_t)(N + M) * 128 * 2);
    float*  Pmin = b2h + M;
    float*  a2   = Pmin + (size_t)N * 8;
    // ws required: 4 MB + 2 MB + 32 KB + 512 KB + 64 KB ≈ 7.0 MB

    prep_kernel<<<Atiles + Btiles, 256, 0, stream>>>(x, self, Aws, Bws, b2h, a2, Atiles);

    int Mslice = M / 4;          // 2048 -> 16 iterations/block
    dim3 grid(Atiles, 4);        // 512 blocks = 2/CU
    min_gemm_kernel<<<grid, 256, 0, stream>>>(Aws, Bws, b2h, Pmin, Mslice);

    final_kernel<<<N / 256, 256, 0, stream>>>(a2, Pmin, out);
}